// Round 8
// baseline (137.910 us; speedup 1.0000x reference)
//
#include <hip/hip_runtime.h>

#define BLOCK 8
#define NGRID 512
#define NROWS_PAD 224   // dedup'd rows (~222) padded to a multiple of 4

// ---------------------------------------------------------------------------
// Compile-time replication of
//   np.random.RandomState(0).choice(np.array([1.0,3.0],f32), size=(512,8))
// (MT19937 legacy scalar seeding, one 32-bit draw per value, value = draw&1).
// Bit i of pattern byte = element i: g[i] = bit ? 3.0f : 1.0f.
// Rows dedup'd in first-occurrence order (argmax-neutral under strict-> scan);
// scan in dedup order with strict > == numpy first-max argmax exactly.
// SCORE PIPELINE BIT-FROZEN (R0/R2/R4/R5/R6 all absmax 0.0078125):
// ascending-i fma chain, lone f32 square, Markstein CR division (residual==0
// for pow2 norms -> one uniform path bit-exact for every norm).
// Padding rows = row-0 clones: equal score never strictly wins.
//
// LAYOUT LESSON (R6): keep tables SoA — plain flat arrays indexed by the
// uniform loop counter batch into s_load_dwordx16; a 48-B AoS struct made the
// compiler serialize load->wait->use (SGPR=32, VALUBusy 50%, 3x slower).
// ---------------------------------------------------------------------------
struct RowTab {
  float q[NROWS_PAD * 8];   // codewords as floats {1,3}, row-major
  float nf[NROWS_PAD];      // norm = 8*(1+popcount)
  float rcf[NROWS_PAD];     // RN(1/nf) (compile-time)
  unsigned pt[NROWS_PAD];   // pattern byte
  int nd;
};

constexpr int popcount8c(unsigned v) {
  int p = 0;
  for (int i = 0; i < 8; ++i) p += (v >> i) & 1u;
  return p;
}

constexpr RowTab make_rowtab() {
  RowTab t{};
  bool exists[256] = {};
  unsigned char pats[256] = {};
  // --- MT19937, numpy legacy scalar seed 0 ---
  unsigned mt[624] = {};
  {
    unsigned s = 0u;
    for (int i = 0; i < 624; ++i) {
      mt[i] = s;
      s = 1812433253u * (s ^ (s >> 30)) + (unsigned)(i + 1);
    }
  }
  int pos = 624;
  int nd = 0;
  for (int j = 0; j < NGRID; ++j) {
    unsigned char b = 0;
    for (int i = 0; i < BLOCK; ++i) {
      if (pos == 624) {
        for (int k = 0; k < 624; ++k) {
          int k1 = (k + 1 < 624) ? k + 1 : 0;
          int k397 = (k + 397 < 624) ? k + 397 : k + 397 - 624;
          unsigned y = (mt[k] & 0x80000000u) | (mt[k1] & 0x7fffffffu);
          unsigned v = mt[k397] ^ (y >> 1);
          if (y & 1u) v ^= 0x9908b0dfu;
          mt[k] = v;
        }
        pos = 0;
      }
      unsigned y = mt[pos++];
      y ^= y >> 11;
      y ^= (y << 7) & 0x9d2c5680u;
      y ^= (y << 15) & 0xefc60000u;
      y ^= y >> 18;
      if (y & 1u) b |= (unsigned char)(1u << i);
    }
    if (!exists[b]) {
      exists[b] = true;
      pats[nd++] = b;
    }
  }
  t.nd = nd;
  for (int j = 0; j < NROWS_PAD; ++j) {
    unsigned b = pats[(j < nd) ? j : 0];   // padding = row-0 clone (never wins)
    for (int i = 0; i < 8; ++i) t.q[j * 8 + i] = ((b >> i) & 1u) ? 3.0f : 1.0f;
    int pc = popcount8c(b);
    float nf = (float)(8 * (1 + pc));
    t.nf[j] = nf;
    t.rcf[j] = 1.0f / nf;                  // RN reciprocal at compile time
    t.pt[j] = b;
  }
  return t;
}

constexpr RowTab RT = make_rowtab();
static_assert(RT.nd > 0 && RT.nd <= NROWS_PAD, "sanity");

// --- materialize as flat SoA __constant__ arrays (batchable s_loads) ---
#define Q1(z) RT.q[z]
#define Q8(z) Q1(z), Q1(z+1), Q1(z+2), Q1(z+3), Q1(z+4), Q1(z+5), Q1(z+6), Q1(z+7)
#define Q64(z) Q8(z), Q8(z+8), Q8(z+16), Q8(z+24), Q8(z+32), Q8(z+40), Q8(z+48), Q8(z+56)
#define Q256(z) Q64(z), Q64(z+64), Q64(z+128), Q64(z+192)
__device__ __constant__ const float g_q[NROWS_PAD * 8] = {
    Q256(0), Q256(256), Q256(512), Q256(768),
    Q256(1024), Q256(1280), Q256(1536)
};
#undef Q256
#undef Q64
#undef Q8
#undef Q1

#define N1(z) RT.nf[z]
#define N8(z) N1(z), N1(z+1), N1(z+2), N1(z+3), N1(z+4), N1(z+5), N1(z+6), N1(z+7)
#define N64(z) N8(z), N8(z+8), N8(z+16), N8(z+24), N8(z+32), N8(z+40), N8(z+48), N8(z+56)
__device__ __constant__ const float g_nf[NROWS_PAD] = {
    N64(0), N64(64), N64(128), N8(192), N8(200), N8(208), N8(216)
};
#undef N64
#undef N8
#undef N1

#define R1(z) RT.rcf[z]
#define R8(z) R1(z), R1(z+1), R1(z+2), R1(z+3), R1(z+4), R1(z+5), R1(z+6), R1(z+7)
#define R64(z) R8(z), R8(z+8), R8(z+16), R8(z+24), R8(z+32), R8(z+40), R8(z+48), R8(z+56)
__device__ __constant__ const float g_rcf[NROWS_PAD] = {
    R64(0), R64(64), R64(128), R8(192), R8(200), R8(208), R8(216)
};
#undef R64
#undef R8
#undef R1

#define T1(z) RT.pt[z]
#define T8(z) T1(z), T1(z+1), T1(z+2), T1(z+3), T1(z+4), T1(z+5), T1(z+6), T1(z+7)
#define T64(z) T8(z), T8(z+8), T8(z+16), T8(z+24), T8(z+32), T8(z+40), T8(z+48), T8(z+56)
__device__ __constant__ const unsigned g_pt[NROWS_PAD] = {
    T64(0), T64(64), T64(128), T8(192), T8(200), T8(208), T8(216)
};
#undef T64
#undef T8
#undef T1

__global__ __launch_bounds__(256, 8) void _IQ2XSQuantWeight_12945031430379_kernel(
    const float* __restrict__ w, float* __restrict__ out, int nb) {
  int t = blockIdx.x * blockDim.x + threadIdx.x;
  if (t >= nb) return;

  const float4* wp = reinterpret_cast<const float4*>(w) + (size_t)2 * t;
  float4 w0 = wp[0];
  float4 w1 = wp[1];
  float wv[BLOCK] = {w0.x, w0.y, w0.z, w0.w, w1.x, w1.y, w1.z, w1.w};

  float a[BLOCK];
  unsigned sb = 0u;   // packed sign bits of w
#pragma unroll
  for (int i = 0; i < BLOCK; ++i) {
    a[i] = __builtin_fabsf(wv[i]);
    sb |= (__float_as_uint(wv[i]) >> 31) << i;
  }

  float gb = -1.0f;     // scores >= 0, first row always wins
  unsigned gpat = 0u;

  // 15-slot row body; table reads are wave-uniform s_loads, batched by unroll.
#pragma unroll 4
  for (int j = 0; j < NROWS_PAD; ++j) {
    float d = 0.0f;
#pragma unroll
    for (int i = 0; i < BLOCK; ++i) d = __builtin_fmaf(a[i], g_q[j * 8 + i], d);
    float dd = d * d;
    // Markstein CR division: == fl32(dd/nf) for every norm.
    float q0 = dd * g_rcf[j];
    float rr = __builtin_fmaf(-g_nf[j], q0, dd);
    float sc = __builtin_fmaf(rr, g_rcf[j], q0);
    // strict >, k-ascending: keep old unless strictly greater (first max).
    bool keep = !(sc > gb);                 // v_cmp_le; no NaNs possible
    gpat = keep ? gpat : g_pt[j];           // cndmask: sgpr in src0, vgpr src1
    gb = __builtin_fmaxf(gb, sc);           // v_max_f32
  }

  // ---- epilogue: bit-identical to R5/R6 (both passed, absmax 0.0078125) ----
  unsigned bits = gpat;

  float p[BLOCK];
#pragma unroll
  for (int i = 0; i < BLOCK; ++i) {
    float a3 = a[i] * 3.0f;
    p[i] = ((bits >> i) & 1u) ? a3 : a[i];
  }
  float num = ((p[0] + p[1]) + (p[2] + p[3])) + ((p[4] + p[5]) + (p[6] + p[7]));

  int popc = __popc(bits);
  float normf = (float)(8 + (popc << 3));
  float scale = num / normf;                // IEEE CR f32 divide (once)
  float s3 = scale * 3.0f;

  float o[BLOCK];
#pragma unroll
  for (int i = 0; i < BLOCK; ++i) {
    float mag = ((bits >> i) & 1u) ? s3 : scale;
    unsigned ob = __float_as_uint(mag) | (((sb >> i) & 1u) << 31);
    float v = __uint_as_float(ob);
    o[i] = (a[i] == 0.0f) ? 0.0f : v;       // copysign + exact-zero guard
  }

  float4 o0 = {o[0], o[1], o[2], o[3]};
  float4 o1 = {o[4], o[5], o[6], o[7]};
  float4* op = reinterpret_cast<float4*>(out) + (size_t)2 * t;
  op[0] = o0;
  op[1] = o1;
}

extern "C" void kernel_launch(void* const* d_in, const int* in_sizes, int n_in,
                              void* d_out, int out_size, void* d_ws, size_t ws_size,
                              hipStream_t stream) {
  (void)n_in; (void)d_ws; (void)ws_size; (void)out_size;
  const float* w = (const float*)d_in[0];
  float* out = (float*)d_out;
  int n = in_sizes[0];
  int nb = n / BLOCK;
  int threads = 256;
  int blocks = (nb + threads - 1) / threads;
  _IQ2XSQuantWeight_12945031430379_kernel<<<blocks, threads, 0, stream>>>(w, out, nb);
}

// Round 9
// 112.560 us; speedup vs baseline: 1.2252x; 1.2252x over previous
//
#include <hip/hip_runtime.h>

#define BLOCK 8
#define NGRID 512
#define NROWS_PAD 224   // dedup'd rows (~222) padded to a multiple of 4

// ---------------------------------------------------------------------------
// R0-clone structure (the only loop measured at ~96% issue efficiency:
// 512 rows -> 60.6us, VALUBusy 75%, SGPR 48). Exactly ONE structural change:
// 512 rows -> 224 dedup'd rows (first-occurrence order; argmax-neutral under
// the strict-> k-ascending scan; padding rows are row-0 clones, never win).
//
// Codebook = compile-time replication of
//   np.random.RandomState(0).choice(np.array([1.0,3.0],f32), size=(512,8))
// (MT19937 legacy scalar seeding, one 32-bit draw per value, value = draw&1).
// SCORE PIPELINE BIT-FROZEN (R0/R2/R4..R7, absmax 0.0078125): ascending-i
// fma chain, lone f32 square, correctly-rounded division via f64 reciprocal
// ((float)((double)dd * RN64(1/n)) == fl32(dd/n) for these norms).
// ---------------------------------------------------------------------------
struct Tabs {
  float g[NROWS_PAD][BLOCK];   // codewords as floats {1,3}, R0's 2D layout
  double dinv[NROWS_PAD];      // RN64(1/norm)
};

struct PatArr {
  unsigned char v[NROWS_PAD];  // dedup index -> pattern byte (epilogue)
};

constexpr int popcount8c(unsigned v) {
  int p = 0;
  for (int i = 0; i < 8; ++i) p += (v >> i) & 1u;
  return p;
}

// MT19937 -> dedup'd pattern list (first-occurrence order)
struct PatList { unsigned char p[NROWS_PAD]; int nd; };

constexpr PatList make_pats() {
  PatList out{};
  bool exists[256] = {};
  unsigned mt[624] = {};
  {
    unsigned s = 0u;
    for (int i = 0; i < 624; ++i) {
      mt[i] = s;
      s = 1812433253u * (s ^ (s >> 30)) + (unsigned)(i + 1);
    }
  }
  int pos = 624;
  int nd = 0;
  for (int j = 0; j < NGRID; ++j) {
    unsigned char b = 0;
    for (int i = 0; i < BLOCK; ++i) {
      if (pos == 624) {
        for (int k = 0; k < 624; ++k) {
          int k1 = (k + 1 < 624) ? k + 1 : 0;
          int k397 = (k + 397 < 624) ? k + 397 : k + 397 - 624;
          unsigned y = (mt[k] & 0x80000000u) | (mt[k1] & 0x7fffffffu);
          unsigned v = mt[k397] ^ (y >> 1);
          if (y & 1u) v ^= 0x9908b0dfu;
          mt[k] = v;
        }
        pos = 0;
      }
      unsigned y = mt[pos++];
      y ^= y >> 11;
      y ^= (y << 7) & 0x9d2c5680u;
      y ^= (y << 15) & 0xefc60000u;
      y ^= y >> 18;
      if (y & 1u) b |= (unsigned char)(1u << i);
    }
    if (!exists[b] && nd < NROWS_PAD) {
      exists[b] = true;
      out.p[nd++] = b;
    }
  }
  out.nd = nd;
  for (int j = nd; j < NROWS_PAD; ++j) out.p[j] = out.p[0];  // row-0 clones
  return out;
}

constexpr PatList PL = make_pats();
static_assert(PL.nd > 200 && PL.nd <= NROWS_PAD, "dedup sanity");

constexpr Tabs make_tabs() {
  Tabs t{};
  for (int j = 0; j < NROWS_PAD; ++j) {
    unsigned b = PL.p[j];
    for (int i = 0; i < BLOCK; ++i) t.g[j][i] = ((b >> i) & 1u) ? 3.0f : 1.0f;
    int n = 8 * (1 + popcount8c(b));
    t.dinv[j] = 1.0 / (double)n;
  }
  return t;
}

constexpr PatArr make_patarr() {
  PatArr a{};
  for (int j = 0; j < NROWS_PAD; ++j) a.v[j] = PL.p[j];
  return a;
}

__constant__ Tabs c_tabs = make_tabs();
__constant__ PatArr c_patk = make_patarr();

__global__ __launch_bounds__(256) void _IQ2XSQuantWeight_12945031430379_kernel(
    const float* __restrict__ w, float* __restrict__ out, int nb) {
  int t = blockIdx.x * blockDim.x + threadIdx.x;
  if (t >= nb) return;

  const float4* wp = reinterpret_cast<const float4*>(w) + (size_t)2 * t;
  float4 w0 = wp[0];
  float4 w1 = wp[1];
  float wv[BLOCK] = {w0.x, w0.y, w0.z, w0.w, w1.x, w1.y, w1.z, w1.w};

  float a[BLOCK];
  unsigned sb = 0u;   // packed sign bits of w
#pragma unroll
  for (int i = 0; i < BLOCK; ++i) {
    a[i] = __builtin_fabsf(wv[i]);
    sb |= (__float_as_uint(wv[i]) >> 31) << i;
  }

  // ---- R0's loop body, verbatim (96%-efficiency structure) ----
  float best = -1.0f;
  int bestk = 0;
#pragma unroll 4
  for (int k = 0; k < NROWS_PAD; ++k) {
    float d = 0.0f;
#pragma unroll
    for (int i = 0; i < BLOCK; ++i) d = __builtin_fmaf(a[i], c_tabs.g[k][i], d);
    float dd = d * d;
    float sc = (float)((double)dd * c_tabs.dinv[k]);
    bool gt = sc > best;
    best = gt ? sc : best;
    bestk = gt ? k : bestk;
  }

  // ---- epilogue: R5's (proven bit-compatible, absmax 0.0078125 x3) ----
  unsigned bits = (unsigned)c_patk.v[bestk];   // divergent 1-byte gather, L1

  float p[BLOCK];
#pragma unroll
  for (int i = 0; i < BLOCK; ++i) {
    float a3 = a[i] * 3.0f;
    p[i] = ((bits >> i) & 1u) ? a3 : a[i];
  }
  float num = ((p[0] + p[1]) + (p[2] + p[3])) + ((p[4] + p[5]) + (p[6] + p[7]));

  int popc = __popc(bits);
  float normf = (float)(8 + (popc << 3));
  float scale = num / normf;                   // IEEE CR f32 divide (once)
  float s3 = scale * 3.0f;

  float o[BLOCK];
#pragma unroll
  for (int i = 0; i < BLOCK; ++i) {
    float mag = ((bits >> i) & 1u) ? s3 : scale;
    unsigned ob = __float_as_uint(mag) | (((sb >> i) & 1u) << 31);
    float v = __uint_as_float(ob);
    o[i] = (a[i] == 0.0f) ? 0.0f : v;          // copysign + exact-zero guard
  }

  float4 o0 = {o[0], o[1], o[2], o[3]};
  float4 o1 = {o[4], o[5], o[6], o[7]};
  float4* op = reinterpret_cast<float4*>(out) + (size_t)2 * t;
  op[0] = o0;
  op[1] = o1;
}

extern "C" void kernel_launch(void* const* d_in, const int* in_sizes, int n_in,
                              void* d_out, int out_size, void* d_ws, size_t ws_size,
                              hipStream_t stream) {
  (void)n_in; (void)d_ws; (void)ws_size; (void)out_size;
  const float* w = (const float*)d_in[0];
  float* out = (float*)d_out;
  int n = in_sizes[0];
  int nb = n / BLOCK;
  int threads = 256;
  int blocks = (nb + threads - 1) / threads;
  _IQ2XSQuantWeight_12945031430379_kernel<<<blocks, threads, 0, stream>>>(w, out, nb);
}

// Round 10
// 86.263 us; speedup vs baseline: 1.5987x; 1.3048x over previous
//
#include <hip/hip_runtime.h>

#define BLOCK 8
#define NGRID 512

// ---------------------------------------------------------------------------
// Compile-time replication of
//   np.random.RandomState(0).choice(np.array([1.0,3.0],f32), size=(512,8))
// (MT19937 legacy scalar seeding, one 32-bit draw per value, value = draw&1).
// Bit i of pattern byte = element i: g[i] = bit ? 3.0f : 1.0f.
// Dedup (first occurrence) is argmax-neutral. kenc = 255 - dedup_index, so
// "ties -> max kenc" == numpy first-max. Scan order = bit-reversed ascending
// (maximizes shared low-bit spine prefixes); selection is order-independent
// under exact (sc, kenc) lexicographic max.
// SCORE PIPELINE BIT-FROZEN (R0/R2/R4..R8, absmax 0.0078125 every time):
// ascending-i fma chain (trie prefixes = identical op sequence), lone f32
// square, exact-pow2 scale or Markstein CR division.
// ---------------------------------------------------------------------------
struct Sched {
  int nd;                       // distinct patterns (~222)
  unsigned char kpat[256];      // kenc -> pattern byte (epilogue gather)
  unsigned char dfs_pat[256];   // scan ordinal -> pattern byte
  unsigned char dfs_ken[256];   // scan ordinal -> kenc
  unsigned char lowbit[256];    // ordinal -> lowest differing bit vs prev
  unsigned char csn[16];        // chunk -> member count (chunks of 16)
  unsigned char cslot[16][16];  // chunk, i -> slot (ordinal & 15), kenc-ascending
  unsigned char cken[16][16];   // chunk, i -> kenc,                kenc-ascending
};

constexpr unsigned char bitrev8c(unsigned v) {
  unsigned r = 0;
  for (int i = 0; i < 8; ++i) r |= ((v >> i) & 1u) << (7 - i);
  return (unsigned char)r;
}
constexpr int popcount8c(int v) {
  int p = 0;
  for (int i = 0; i < 8; ++i) p += (v >> i) & 1;
  return p;
}
constexpr int ctz8c(int v) {
  for (int i = 0; i < 8; ++i) if ((v >> i) & 1) return i;
  return 0;
}

constexpr Sched make_sched() {
  Sched t{};
  bool exists[256] = {};
  unsigned char kenc[256] = {};
  unsigned mt[624] = {};
  {
    unsigned s = 0u;
    for (int i = 0; i < 624; ++i) {
      mt[i] = s;
      s = 1812433253u * (s ^ (s >> 30)) + (unsigned)(i + 1);
    }
  }
  int pos = 624;
  int nd = 0;
  for (int j = 0; j < NGRID; ++j) {
    unsigned char b = 0;
    for (int i = 0; i < BLOCK; ++i) {
      if (pos == 624) {
        for (int k = 0; k < 624; ++k) {
          int k1 = (k + 1 < 624) ? k + 1 : 0;
          int k397 = (k + 397 < 624) ? k + 397 : k + 397 - 624;
          unsigned y = (mt[k] & 0x80000000u) | (mt[k1] & 0x7fffffffu);
          unsigned v = mt[k397] ^ (y >> 1);
          if (y & 1u) v ^= 0x9908b0dfu;
          mt[k] = v;
        }
        pos = 0;
      }
      unsigned y = mt[pos++];
      y ^= y >> 11;
      y ^= (y << 7) & 0x9d2c5680u;
      y ^= (y << 15) & 0xefc60000u;
      y ^= y >> 18;
      if (y & 1u) b |= (unsigned char)(1u << i);
    }
    if (!exists[b]) {
      exists[b] = true;
      kenc[b] = (unsigned char)(255 - nd);
      t.kpat[255 - nd] = b;
      ++nd;
    }
  }
  t.nd = nd;
  int m = 0;
  for (int r = 0; r < 256; ++r) {
    unsigned char b = bitrev8c((unsigned)r);
    if (exists[b]) {
      t.dfs_pat[m] = b;
      t.dfs_ken[m] = kenc[b];
      ++m;
    }
  }
  t.lowbit[0] = 0;
  for (int j = 1; j < nd; ++j)
    t.lowbit[j] = (unsigned char)ctz8c(t.dfs_pat[j] ^ t.dfs_pat[j - 1]);
  // chunks of 16, members sorted by kenc ascending (insertion sort)
  int nc = (nd + 15) / 16;
  for (int c = 0; c < nc; ++c) {
    int n = nd - 16 * c; if (n > 16) n = 16;
    t.csn[c] = (unsigned char)n;
    unsigned char sl[16] = {}, ke[16] = {};
    for (int i = 0; i < n; ++i) { sl[i] = (unsigned char)i; ke[i] = t.dfs_ken[16 * c + i]; }
    for (int i = 1; i < n; ++i) {
      unsigned char ks = ke[i], ss = sl[i];
      int p = i - 1;
      while (p >= 0 && ke[p] > ks) { ke[p + 1] = ke[p]; sl[p + 1] = sl[p]; --p; }
      ke[p + 1] = ks; sl[p + 1] = ss;
    }
    for (int i = 0; i < n; ++i) { t.cslot[c][i] = sl[i]; t.cken[c][i] = ke[i]; }
  }
  return t;
}

constexpr Sched SC = make_sched();
constexpr int ND = SC.nd;
static_assert(ND > 0 && ND <= 256, "sanity");

// epilogue gather table: kenc -> pattern byte (L1-resident)
__device__ __constant__ const unsigned char g_pat[256] = {
#define P1(z) SC.kpat[z]
#define P8(z) P1(z), P1(z+1), P1(z+2), P1(z+3), P1(z+4), P1(z+5), P1(z+6), P1(z+7)
#define P64(z) P8(z), P8(z+8), P8(z+16), P8(z+24), P8(z+32), P8(z+40), P8(z+48), P8(z+56)
    P64(0), P64(64), P64(128), P64(192)
#undef P64
#undef P8
#undef P1
};

// ---------------------------------------------------------------------------
// Trie scan step, ordinal J (R4's proven structure; chunks widened to 16 and
// klut replaced by direct literal-kenc cndmask in the eq-scan).
// ---------------------------------------------------------------------------
template <int J>
struct Step {
  static __device__ __forceinline__ void run(const float (&a)[BLOCK], float (&sp)[9],
                                             float (&scs)[16], float &gb, int &gk) {
    constexpr int pat = SC.dfs_pat[J];
    constexpr int p0 = (J == 0) ? 0 : SC.lowbit[J];
#pragma unroll
    for (int l = 0; l < 8; ++l) {
      if (l >= p0) {
        if ((pat >> l) & 1)
          sp[l + 1] = __builtin_fmaf(a[l], 3.0f, sp[l]);
        else
          sp[l + 1] = sp[l] + a[l];
      }
    }
    float d = sp[8];
    float dd = d * d;
    constexpr int pc = popcount8c(pat);
    float sc;
    if constexpr (pc == 0)      sc = dd * 0.125f;      // /8   exact
    else if constexpr (pc == 1) sc = dd * 0.0625f;     // /16  exact
    else if constexpr (pc == 3) sc = dd * 0.03125f;    // /32  exact
    else if constexpr (pc == 7) sc = dd * 0.015625f;   // /64  exact
    else {
      constexpr float nf = (float)(8 * (1 + pc));
      constexpr float rcf = 1.0f / nf;
      float q0 = dd * rcf;
      float r = __builtin_fmaf(-nf, q0, dd);           // exact residual
      sc = __builtin_fmaf(r, rcf, q0);                 // Markstein: == fl32(dd/nf)
    }
    scs[J & 15] = sc;

    if constexpr (((J & 15) == 15) || (J == ND - 1)) {
      constexpr int c = J >> 4;
      constexpr int n = SC.csn[c];
      // chunk max: pairwise fmax tree (no vcc)
      float cm;
      if constexpr (n == 16) {
        float m0 = __builtin_fmaxf(__builtin_fmaxf(scs[0], scs[1]),
                                   __builtin_fmaxf(scs[2], scs[3]));
        float m1 = __builtin_fmaxf(__builtin_fmaxf(scs[4], scs[5]),
                                   __builtin_fmaxf(scs[6], scs[7]));
        float m2 = __builtin_fmaxf(__builtin_fmaxf(scs[8], scs[9]),
                                   __builtin_fmaxf(scs[10], scs[11]));
        float m3 = __builtin_fmaxf(__builtin_fmaxf(scs[12], scs[13]),
                                   __builtin_fmaxf(scs[14], scs[15]));
        cm = __builtin_fmaxf(__builtin_fmaxf(m0, m1), __builtin_fmaxf(m2, m3));
      } else {
        cm = scs[0];
#pragma unroll
        for (int i = 1; i < n; ++i) cm = __builtin_fmaxf(cm, scs[i]);
      }
      // winner kenc: kenc-ascending eq-scan, last equal write = min original k.
      // Reversed compare so the kenc literal sits in cndmask src0 (VOP2 form).
      int mk = 0;
#pragma unroll
      for (int i = 0; i < n; ++i)
        mk = (scs[SC.cslot[c][i]] != cm) ? mk : (int)SC.cken[c][i];
      // exact cross-chunk merge (proven in R4): lexicographic (sc, kenc) max
      bool r = (cm > gb) || ((cm == gb) && (mk > gk));
      gb = r ? cm : gb;
      gk = r ? mk : gk;
    }
    if constexpr (J + 1 < ND) Step<J + 1>::run(a, sp, scs, gb, gk);
  }
};

__global__ __launch_bounds__(256, 8) void _IQ2XSQuantWeight_12945031430379_kernel(
    const float* __restrict__ w, float* __restrict__ out, int nb) {
  int t = blockIdx.x * blockDim.x + threadIdx.x;
  if (t >= nb) return;

  const float4* wp = reinterpret_cast<const float4*>(w) + (size_t)2 * t;
  float4 w0 = wp[0];
  float4 w1 = wp[1];
  float wv[BLOCK] = {w0.x, w0.y, w0.z, w0.w, w1.x, w1.y, w1.z, w1.w};

  float a[BLOCK];
  unsigned sb = 0u;   // packed sign bits of w
#pragma unroll
  for (int i = 0; i < BLOCK; ++i) {
    a[i] = __builtin_fabsf(wv[i]);
    sb |= (__float_as_uint(wv[i]) >> 31) << i;
  }

  float sp[9];
  sp[0] = 0.0f;
  float scs[16];
  float gb = -1.0f;
  int gk = 0;
  Step<0>::run(a, sp, scs, gb, gk);

  // ---- epilogue: bit-identical to R4/R5 (proven absmax 0.0078125) ----
  unsigned bits = (unsigned)g_pat[gk];   // divergent 1-byte gather, L1

  float p[BLOCK];
#pragma unroll
  for (int i = 0; i < BLOCK; ++i) {
    float a3 = a[i] * 3.0f;
    p[i] = ((bits >> i) & 1u) ? a3 : a[i];
  }
  float num = ((p[0] + p[1]) + (p[2] + p[3])) + ((p[4] + p[5]) + (p[6] + p[7]));

  int popc = __popc(bits);
  float normf = (float)(8 + (popc << 3));
  float scale = num / normf;             // IEEE CR f32 divide (once)
  float s3 = scale * 3.0f;

  float o[BLOCK];
#pragma unroll
  for (int i = 0; i < BLOCK; ++i) {
    float mag = ((bits >> i) & 1u) ? s3 : scale;
    unsigned ob = __float_as_uint(mag) | (((sb >> i) & 1u) << 31);
    float v = __uint_as_float(ob);
    o[i] = (a[i] == 0.0f) ? 0.0f : v;    // copysign + exact-zero guard
  }

  float4 o0 = {o[0], o[1], o[2], o[3]};
  float4 o1 = {o[4], o[5], o[6], o[7]};
  float4* op = reinterpret_cast<float4*>(out) + (size_t)2 * t;
  op[0] = o0;
  op[1] = o1;
}

extern "C" void kernel_launch(void* const* d_in, const int* in_sizes, int n_in,
                              void* d_out, int out_size, void* d_ws, size_t ws_size,
                              hipStream_t stream) {
  (void)n_in; (void)d_ws; (void)ws_size; (void)out_size;
  const float* w = (const float*)d_in[0];
  float* out = (float*)d_out;
  int n = in_sizes[0];
  int nb = n / BLOCK;
  int threads = 256;
  int blocks = (nb + threads - 1) / threads;
  _IQ2XSQuantWeight_12945031430379_kernel<<<blocks, threads, 0, stream>>>(w, out, nb);
}